// Round 1
// baseline (997.204 us; speedup 1.0000x reference)
//
#include <hip/hip_runtime.h>
#include <stdint.h>

// WordLSTMCell: c1 = sigmoid(f)*c0 + sigmoid(i)*tanh(c),
//   [f|i|c] = x@W + h@Wh + b ;  x:[8192,1024] h,c0:[8192,2048]
//   W:[1024,6144] Wh:[2048,6144] b:[6144]  (all fp32; out fp32 [8192,2048])
//
// Round 3: K-loop was latency-bound (MfmaUtil 29%, HBM 9.6%): __syncthreads
// right after the global_load_lds issue drained vmcnt(0) with ZERO cover.
// Changes:
//  - A LDS double-buffered (2 x 8 KB): stage kt+1 at the top of iter kt,
//    ONE raw s_barrier per kt with the vmcnt/lgkm drain AFTER the MFMAs
//    (T3 minimum 2-phase recipe) -> stage gets a full body of cover, and
//    barrier count halves.
//  - s_setprio(1) around the MFMA cluster.
//  - XCD-bijective block remap: same-XCD blocks share an A row-panel (mt)
//    and sweep jt -> each A panel is fetched from HBM by exactly one XCD;
//    streamed B frags stay L2-resident (lower latency on the drains).

#define BATCH 8192
#define INSZ  1024
#define HID   2048
#define NG    6144
#define KTOT  3072
#define KTILES 96

typedef __attribute__((ext_vector_type(8))) short short8;
typedef __attribute__((ext_vector_type(4))) short short4v;
typedef __attribute__((ext_vector_type(4))) float f32x4;
typedef __attribute__((ext_vector_type(4))) unsigned short u16x4;

__device__ __forceinline__ unsigned short f32_to_bf16(float f) {
  uint32_t u = __builtin_bit_cast(uint32_t, f);
  u += 0x7fffu + ((u >> 16) & 1u);   // round-to-nearest-even
  return (unsigned short)(u >> 16);
}

// ---------------- pack kernels (Path A) ----------------

// Apack[kt][m][chunk-swizzled 32] = concat(x,h)[m][kt*32+..], bf16. 48 MB.
// Within each 64B row, 16B chunk c stored at c ^ ((m + (m>>2)) & 3).
__global__ __launch_bounds__(256) void pack_a_kernel(
    const float* __restrict__ x, const float* __restrict__ h,
    unsigned short* __restrict__ Ap) {
  uint32_t q   = blockIdx.x * 256u + threadIdx.x;  // [0, 96*8192*8)
  uint32_t kk4 = q & 7u;           // half-chunk index (4 floats)
  uint32_t m   = (q >> 3) & 8191u;
  uint32_t kt  = q >> 16;
  uint32_t k   = kt * 32u + kk4 * 4u;
  const float* src = (k < INSZ) ? (x + (size_t)m * INSZ + k)
                                : (h + (size_t)m * HID + (k - INSZ));
  float4 v = *(const float4*)src;
  u16x4 o;
  o.x = f32_to_bf16(v.x); o.y = f32_to_bf16(v.y);
  o.z = f32_to_bf16(v.z); o.w = f32_to_bf16(v.w);
  uint32_t c  = kk4 >> 1, hh = kk4 & 1;
  uint32_t sm = (m + (m >> 2)) & 3u;
  *(u16x4*)(Ap + ((size_t)kt * BATCH + m) * 32 + ((c ^ sm) * 8 + hh * 4)) = o;
}

// Bpack[kt][n][kk] = vstack(W,Wh)[kt*32+kk][n], bf16. 36 MB. No LDS:
// strided reads (8x32B segments/wave), fully coalesced 8B stores.
__global__ __launch_bounds__(256) void pack_b_kernel(
    const float* __restrict__ W, const float* __restrict__ Wh,
    unsigned short* __restrict__ Bp) {
  uint32_t q  = blockIdx.x * 256u + threadIdx.x;  // [0, 96*6144*8)
  uint32_t hh = q & 7u;                            // u16x4 within row
  uint32_t r  = q >> 3;
  uint32_t n  = r % 6144u;
  uint32_t kt = r / 6144u;
  uint32_t k0 = kt * 32u + hh * 4u;
  float v[4];
#pragma unroll
  for (int t = 0; t < 4; ++t) {
    uint32_t k = k0 + t;
    v[t] = (k < INSZ) ? W[(size_t)k * NG + n]
                      : Wh[(size_t)(k - INSZ) * NG + n];
  }
  u16x4 o;
  o.x = f32_to_bf16(v[0]); o.y = f32_to_bf16(v[1]);
  o.z = f32_to_bf16(v[2]); o.w = f32_to_bf16(v[3]);
  *(u16x4*)(Bp + ((size_t)kt * NG + n) * 32 + hh * 4) = o;
}

// ---------------- shared epilogue ----------------
// C-layout (m89-verified): col = lane&15, row = (lane>>4)*4 + reg.
__device__ __forceinline__ void lstm_epilogue(
    const f32x4 acc[4][6], int m0, int j0, int wm, int wn, int quad, int l16,
    const float* __restrict__ bias, const float* __restrict__ c0,
    float* __restrict__ out) {
#pragma unroll
  for (int mi = 0; mi < 4; ++mi) {
    int rowb = m0 + wm * 64 + mi * 16 + quad * 4;
#pragma unroll
    for (int p = 0; p < 2; ++p) {
      int j = j0 + (2 * wn + p) * 16 + l16;
      float bfv = bias[j], biv = bias[HID + j], bcv = bias[2 * HID + j];
#pragma unroll
      for (int r = 0; r < 4; ++r) {
        size_t idx = (size_t)(rowb + r) * HID + j;
        float fg = acc[mi][0 + p][r] + bfv;
        float ig = acc[mi][2 + p][r] + biv;
        float cg = acc[mi][4 + p][r] + bcv;
        float sf = 1.f / (1.f + __expf(-fg));
        float si = 1.f / (1.f + __expf(-ig));
        float th = 2.f / (1.f + __expf(-2.f * cg)) - 1.f;
        out[idx] = sf * c0[idx] + si * th;
      }
    }
  }
}

// ---------------- Path A GEMM: A dbuf-LDS (swizzled), B register-direct ----
__global__ __launch_bounds__(256) void gemm_packed_kernel(
    const unsigned short* __restrict__ Ap, const unsigned short* __restrict__ Bp,
    const float* __restrict__ bias, const float* __restrict__ c0,
    float* __restrict__ out) {
  __shared__ __align__(16) unsigned short As[2][128 * 32];  // 2 x 8 KB, swizzled rows
  const int tid = threadIdx.x;
  const int lane = tid & 63, w = tid >> 6;
  const int wm = w >> 1, wn = w & 1;       // waves 2(M) x 2(N-pairs)
  const int quad = lane >> 4, l16 = lane & 15;
  // XCD-bijective remap: blocks with the same (bx & 7) land on one XCD and
  // share an A row-panel (mt) while sweeping jt -> A fetched once per panel.
  const int bx = blockIdx.x;
  const int xcd = bx & 7, blin = bx >> 3;
  const int jt = blin & 31;
  const int mt = ((blin >> 5) << 3) | xcd;
  const int m0 = mt * 128, j0 = jt * 64;
  const int sw = (l16 + (l16 >> 2)) & 3;   // A-row bank swizzle (uniform in mi)

  f32x4 acc[4][6];
#pragma unroll
  for (int a = 0; a < 4; ++a)
#pragma unroll
    for (int b = 0; b < 6; ++b) acc[a][b] = (f32x4){0.f, 0.f, 0.f, 0.f};

  // B fragment base: frag(g,p) at bb + kt*NG*32 + g*(HID*32) + p*512 (shorts)
  const unsigned short* bb =
      Bp + ((size_t)(j0 + 2 * wn * 16 + l16)) * 32 + quad * 8;

  // ---- prologue: stage A(0) -> As[0]; load B(0) -> bf[0] ----
  {
    const unsigned short* ga = Ap + (size_t)m0 * 32;
#pragma unroll
    for (int i = 0; i < 2; ++i) {
      int t2 = w * 2 + i;
      __builtin_amdgcn_global_load_lds(
          (__attribute__((address_space(1))) void*)(void*)(ga + t2 * 512 + lane * 8),
          (__attribute__((address_space(3))) void*)(&As[0][0] + t2 * 512), 16, 0, 0);
    }
  }
  short8 bf[2][6];
#pragma unroll
  for (int g = 0; g < 3; ++g)
#pragma unroll
    for (int p = 0; p < 2; ++p)
      bf[0][g * 2 + p] = *(const short8*)(bb + g * (HID * 32) + p * 512);
  asm volatile("s_waitcnt vmcnt(0)" ::: "memory");
  __builtin_amdgcn_s_barrier();
  __builtin_amdgcn_sched_barrier(0);

  // ---- main loop: ONE barrier per kt, drain AFTER the MFMAs ----
#pragma unroll 2
  for (int kt = 0; kt < KTILES; ++kt) {
    const int cur = kt & 1;
    if (kt + 1 < KTILES) {
      // issue-early: stage A(kt+1) into the other buffer + prefetch B(kt+1);
      // both get the ds_read + 24-MFMA body as latency cover before the drain.
      const unsigned short* ga = Ap + ((size_t)(kt + 1) * BATCH + m0) * 32;
#pragma unroll
      for (int i = 0; i < 2; ++i) {
        int t2 = w * 2 + i;
        __builtin_amdgcn_global_load_lds(
            (__attribute__((address_space(1))) void*)(void*)(ga + t2 * 512 + lane * 8),
            (__attribute__((address_space(3))) void*)(&As[cur ^ 1][0] + t2 * 512),
            16, 0, 0);
      }
      const unsigned short* bn = bb + (size_t)(kt + 1) * ((size_t)NG * 32);
#pragma unroll
      for (int g = 0; g < 3; ++g)
#pragma unroll
        for (int p = 0; p < 2; ++p)
          bf[cur ^ 1][g * 2 + p] = *(const short8*)(bn + g * (HID * 32) + p * 512);
    }
    short8 af[4];
#pragma unroll
    for (int mi = 0; mi < 4; ++mi)  // A-frag: A[m=l16][k=quad*8+j], de-swizzled
      af[mi] = *(const short8*)(
          &As[cur][0] + (wm * 64 + mi * 16 + l16) * 32 + ((quad ^ sw) * 8));
    __builtin_amdgcn_s_setprio(1);
#pragma unroll
    for (int mi = 0; mi < 4; ++mi)
#pragma unroll
      for (int f = 0; f < 6; ++f)
        acc[mi][f] =
            __builtin_amdgcn_mfma_f32_16x16x32_bf16(af[mi], bf[cur][f], acc[mi][f], 0, 0, 0);
    __builtin_amdgcn_s_setprio(0);
    // drain: A(kt+1) staged by THIS wave + its B(kt+1) regs; barrier makes all
    // waves' stage slices visible. ds_reads already lgkm-drained by MFMA deps,
    // the explicit lgkmcnt(0) is belt-and-braces before s_barrier.
    asm volatile("s_waitcnt vmcnt(0) lgkmcnt(0)" ::: "memory");
    __builtin_amdgcn_s_barrier();
    __builtin_amdgcn_sched_barrier(0);
  }
  lstm_epilogue(acc, m0, j0, wm, wn, quad, l16, bias, c0, out);
}

// ---------------- Path B GEMM: fp32 staging fallback (no workspace) --------
__global__ __launch_bounds__(256) void gemm_f32_kernel(
    const float* __restrict__ x, const float* __restrict__ h,
    const float* __restrict__ W, const float* __restrict__ Wh,
    const float* __restrict__ bias, const float* __restrict__ c0,
    float* __restrict__ out) {
  __shared__ __align__(16) unsigned short As[128 * 36];  // 72B rows (pad)
  __shared__ __align__(16) unsigned short Bs[192 * 36];
  const int tid = threadIdx.x;
  const int lane = tid & 63, w = tid >> 6;
  const int wm = w >> 1, wn = w & 1;
  const int quad = lane >> 4, l16 = lane & 15;
  const int bx = blockIdx.x;
  const int jt = bx & 31, mt = bx >> 5;
  const int m0 = mt * 128, j0 = jt * 64;

  f32x4 acc[4][6];
#pragma unroll
  for (int a = 0; a < 4; ++a)
#pragma unroll
    for (int b = 0; b < 6; ++b) acc[a][b] = (f32x4){0.f, 0.f, 0.f, 0.f};

  for (int kt = 0; kt < KTILES; ++kt) {
    int k0 = kt * 32;
#pragma unroll
    for (int i = 0; i < 4; ++i) {
      int q = i * 256 + tid;
      int m = q >> 3, kk = (q & 7) * 4;
      int k = k0 + kk;
      const float* src = (k < INSZ) ? (x + (size_t)(m0 + m) * INSZ + k)
                                    : (h + (size_t)(m0 + m) * HID + (k - INSZ));
      float4 v = *(const float4*)src;
      u16x4 o;
      o.x = f32_to_bf16(v.x); o.y = f32_to_bf16(v.y);
      o.z = f32_to_bf16(v.z); o.w = f32_to_bf16(v.w);
      *(u16x4*)(As + m * 36 + kk) = o;
    }
#pragma unroll
    for (int i = 0; i < 6; ++i) {
      int q = i * 256 + tid;
      int n = q % 192, kq = (q / 192) * 4;
      int col = (n >> 6) * HID + j0 + (n & 63);
      float vv[4];
#pragma unroll
      for (int t = 0; t < 4; ++t) {
        int k = k0 + kq + t;
        vv[t] = (k < INSZ) ? W[(size_t)k * NG + col]
                           : Wh[(size_t)(k - INSZ) * NG + col];
      }
      u16x4 o;
      o.x = f32_to_bf16(vv[0]); o.y = f32_to_bf16(vv[1]);
      o.z = f32_to_bf16(vv[2]); o.w = f32_to_bf16(vv[3]);
      *(u16x4*)(Bs + n * 36 + kq) = o;
    }
    __syncthreads();
    short8 af[4], bf[6];
#pragma unroll
    for (int mi = 0; mi < 4; ++mi) {
      int base = (wm * 64 + mi * 16 + l16) * 36 + quad * 8;
      short4v lo = *(const short4v*)(As + base);
      short4v hi = *(const short4v*)(As + base + 4);
      af[mi] = __builtin_shufflevector(lo, hi, 0, 1, 2, 3, 4, 5, 6, 7);
    }
#pragma unroll
    for (int g = 0; g < 3; ++g)
#pragma unroll
      for (int p = 0; p < 2; ++p) {
        int base = (g * 64 + (2 * wn + p) * 16 + l16) * 36 + quad * 8;
        short4v lo = *(const short4v*)(Bs + base);
        short4v hi = *(const short4v*)(Bs + base + 4);
        bf[g * 2 + p] = __builtin_shufflevector(lo, hi, 0, 1, 2, 3, 4, 5, 6, 7);
      }
#pragma unroll
    for (int mi = 0; mi < 4; ++mi)
#pragma unroll
      for (int f = 0; f < 6; ++f)
        acc[mi][f] =
            __builtin_amdgcn_mfma_f32_16x16x32_bf16(af[mi], bf[f], acc[mi][f], 0, 0, 0);
    __syncthreads();
  }
  lstm_epilogue(acc, m0, j0, wm, wn, quad, l16, bias, c0, out);
}

extern "C" void kernel_launch(void* const* d_in, const int* in_sizes, int n_in,
                              void* d_out, int out_size, void* d_ws, size_t ws_size,
                              hipStream_t stream) {
  const float* x    = (const float*)d_in[0];
  const float* h0   = (const float*)d_in[1];
  const float* c0   = (const float*)d_in[2];
  const float* W    = (const float*)d_in[3];
  const float* Wh   = (const float*)d_in[4];
  const float* bias = (const float*)d_in[5];
  float* out = (float*)d_out;

  const size_t needA = (size_t)KTOT * BATCH * 2;  // 48 MB
  const size_t needB = (size_t)KTOT * NG * 2;     // 36 MB
  if (ws_size >= needA + needB) {
    unsigned short* Ap = (unsigned short*)d_ws;
    unsigned short* Bp = Ap + (size_t)KTOT * BATCH;
    pack_a_kernel<<<24576, 256, 0, stream>>>(x, h0, Ap);
    pack_b_kernel<<<18432, 256, 0, stream>>>(W, Wh, Bp);
    gemm_packed_kernel<<<2048, 256, 0, stream>>>(Ap, Bp, bias, c0, out);
  } else {
    gemm_f32_kernel<<<2048, 256, 0, stream>>>(x, h0, W, Wh, bias, c0, out);
  }
}

// Round 2
// 824.626 us; speedup vs baseline: 1.2093x; 1.2093x over previous
//
#include <hip/hip_runtime.h>
#include <stdint.h>

// WordLSTMCell: c1 = sigmoid(f)*c0 + sigmoid(i)*tanh(c),
//   [f|i|c] = x@W + h@Wh + b ;  x:[8192,1024] h,c0:[8192,2048]
//   W:[1024,6144] Wh:[2048,6144] b:[6144]  (all fp32; out fp32 [8192,2048])
//
// Round 4:
//  - REVERT the XCD remap (FETCH 279MB->1.24GB regression: inputs are L3-fit;
//    old mapping keeps co-resident blocks on one B-slice -> L2-resident).
//  - Deepen the pipeline: 3-buffer A LDS, stage A(kt+2) + B(kt+1) at the top
//    of iter kt, ONE s_barrier per kt with COUNTED s_waitcnt vmcnt(26)
//    (never 0 in the loop -> no drain; A gets ~2 iterations of cover,
//    B gets body+barrier cover via the compiler's vmcnt(14) before MFMAs).
//  - Branch-free tail: out-of-range prefetches clamp to the last tile and
//    land in an unread buffer (keeps the vmcnt arithmetic uniform).
//  - pack_a/pack_b fused into one dispatch (one less launch gap).

#define BATCH 8192
#define INSZ  1024
#define HID   2048
#define NG    6144
#define KTOT  3072
#define KTILES 96

typedef __attribute__((ext_vector_type(8))) short short8;
typedef __attribute__((ext_vector_type(4))) short short4v;
typedef __attribute__((ext_vector_type(4))) float f32x4;
typedef __attribute__((ext_vector_type(4))) unsigned short u16x4;

__device__ __forceinline__ unsigned short f32_to_bf16(float f) {
  uint32_t u = __builtin_bit_cast(uint32_t, f);
  u += 0x7fffu + ((u >> 16) & 1u);   // round-to-nearest-even
  return (unsigned short)(u >> 16);
}

// ---------------- fused pack kernel (Path A) ----------------
// Part A (blocks [0,24576)):
//   Apack[kt][m][chunk-swizzled 32] = concat(x,h)[m][kt*32+..], bf16. 48 MB.
//   Within each 64B row, 16B chunk c stored at c ^ ((m + (m>>2)) & 3).
// Part B (blocks [24576,43008)):
//   Bpack[kt][n][kk] = vstack(W,Wh)[kt*32+kk][n], bf16. 36 MB.
#define PACKA_BLOCKS 24576
#define PACKB_BLOCKS 18432
__global__ __launch_bounds__(256) void pack_ab_kernel(
    const float* __restrict__ x, const float* __restrict__ h,
    const float* __restrict__ W, const float* __restrict__ Wh,
    unsigned short* __restrict__ Ap, unsigned short* __restrict__ Bp) {
  if (blockIdx.x < PACKA_BLOCKS) {
    uint32_t q   = blockIdx.x * 256u + threadIdx.x;  // [0, 96*8192*8)
    uint32_t kk4 = q & 7u;           // half-chunk index (4 floats)
    uint32_t m   = (q >> 3) & 8191u;
    uint32_t kt  = q >> 16;
    uint32_t k   = kt * 32u + kk4 * 4u;
    const float* src = (k < INSZ) ? (x + (size_t)m * INSZ + k)
                                  : (h + (size_t)m * HID + (k - INSZ));
    float4 v = *(const float4*)src;
    u16x4 o;
    o.x = f32_to_bf16(v.x); o.y = f32_to_bf16(v.y);
    o.z = f32_to_bf16(v.z); o.w = f32_to_bf16(v.w);
    uint32_t c  = kk4 >> 1, hh = kk4 & 1;
    uint32_t sm = (m + (m >> 2)) & 3u;
    *(u16x4*)(Ap + ((size_t)kt * BATCH + m) * 32 + ((c ^ sm) * 8 + hh * 4)) = o;
  } else {
    uint32_t q  = (blockIdx.x - PACKA_BLOCKS) * 256u + threadIdx.x;  // [0, 96*6144*8)
    uint32_t hh = q & 7u;                            // u16x4 within row
    uint32_t r  = q >> 3;
    uint32_t n  = r % 6144u;
    uint32_t kt = r / 6144u;
    uint32_t k0 = kt * 32u + hh * 4u;
    float v[4];
#pragma unroll
    for (int t = 0; t < 4; ++t) {
      uint32_t k = k0 + t;
      v[t] = (k < INSZ) ? W[(size_t)k * NG + n]
                        : Wh[(size_t)(k - INSZ) * NG + n];
    }
    u16x4 o;
    o.x = f32_to_bf16(v[0]); o.y = f32_to_bf16(v[1]);
    o.z = f32_to_bf16(v[2]); o.w = f32_to_bf16(v[3]);
    *(u16x4*)(Bp + ((size_t)kt * NG + n) * 32 + hh * 4) = o;
  }
}

// ---------------- shared epilogue ----------------
// C-layout (m89-verified): col = lane&15, row = (lane>>4)*4 + reg.
__device__ __forceinline__ void lstm_epilogue(
    const f32x4 acc[4][6], int m0, int j0, int wm, int wn, int quad, int l16,
    const float* __restrict__ bias, const float* __restrict__ c0,
    float* __restrict__ out) {
#pragma unroll
  for (int mi = 0; mi < 4; ++mi) {
    int rowb = m0 + wm * 64 + mi * 16 + quad * 4;
#pragma unroll
    for (int p = 0; p < 2; ++p) {
      int j = j0 + (2 * wn + p) * 16 + l16;
      float bfv = bias[j], biv = bias[HID + j], bcv = bias[2 * HID + j];
#pragma unroll
      for (int r = 0; r < 4; ++r) {
        size_t idx = (size_t)(rowb + r) * HID + j;
        float fg = acc[mi][0 + p][r] + bfv;
        float ig = acc[mi][2 + p][r] + biv;
        float cg = acc[mi][4 + p][r] + bcv;
        float sf = 1.f / (1.f + __expf(-fg));
        float si = 1.f / (1.f + __expf(-ig));
        float th = 2.f / (1.f + __expf(-2.f * cg)) - 1.f;
        out[idx] = sf * c0[idx] + si * th;
      }
    }
  }
}

// ---------------- Path A GEMM: A 3-buf LDS (swizzled), B register-direct ----
__global__ __launch_bounds__(256) void gemm_packed_kernel(
    const unsigned short* __restrict__ Ap, const unsigned short* __restrict__ Bp,
    const float* __restrict__ bias, const float* __restrict__ c0,
    float* __restrict__ out) {
  __shared__ __align__(16) unsigned short As[3][128 * 32];  // 3 x 8 KB, swizzled rows
  const int tid = threadIdx.x;
  const int lane = tid & 63, w = tid >> 6;
  const int wm = w >> 1, wn = w & 1;       // waves 2(M) x 2(N-pairs)
  const int quad = lane >> 4, l16 = lane & 15;
  const int bx = blockIdx.x;
  const int mt = bx & 63, jt = bx >> 6;    // co-resident blocks share jt (B slice)
  const int m0 = mt * 128, j0 = jt * 64;
  const int sw = (l16 + (l16 >> 2)) & 3;   // A-row bank swizzle (uniform in mi)

  f32x4 acc[4][6];
#pragma unroll
  for (int a = 0; a < 4; ++a)
#pragma unroll
    for (int b = 0; b < 6; ++b) acc[a][b] = (f32x4){0.f, 0.f, 0.f, 0.f};

  // B fragment base: frag(g,p) at bb + kt*NG*32 + g*(HID*32) + p*512 (shorts)
  const unsigned short* bb =
      Bp + ((size_t)(j0 + 2 * wn * 16 + l16)) * 32 + quad * 8;

#define STAGE_A(ktile, buf)                                                    \
  {                                                                            \
    const unsigned short* ga = Ap + ((size_t)(ktile) * BATCH + m0) * 32;       \
    _Pragma("unroll")                                                          \
    for (int i = 0; i < 2; ++i) {                                              \
      int t2 = w * 2 + i;                                                      \
      __builtin_amdgcn_global_load_lds(                                        \
          (__attribute__((address_space(1))) void*)(void*)(ga + t2 * 512 +     \
                                                           lane * 8),          \
          (__attribute__((address_space(3))) void*)(&As[(buf)][0] + t2 * 512), \
          16, 0, 0);                                                           \
    }                                                                          \
  }

#define LOAD_B(ktile, idx)                                                     \
  {                                                                            \
    const unsigned short* bn = bb + (size_t)(ktile) * ((size_t)NG * 32);       \
    _Pragma("unroll")                                                          \
    for (int g = 0; g < 3; ++g)                                                \
      _Pragma("unroll")                                                        \
      for (int p = 0; p < 2; ++p)                                              \
        bf[(idx)][g * 2 + p] = *(const short8*)(bn + g * (HID * 32) + p * 512);\
  }

  short8 bf[2][6];
  // ---- prologue: A(0)->As[0], A(1)->As[1], B(0)->bf[0] (14 loads) ----
  STAGE_A(0, 0);
  STAGE_A(1, 1);
  LOAD_B(0, 0);
  // A(0)'s 2 loads have exactly 14 newer (A(1):2 + B(0):12) -> counted wait.
  asm volatile("s_waitcnt vmcnt(14)" ::: "memory");
  __builtin_amdgcn_s_barrier();
  __builtin_amdgcn_sched_barrier(0);

  // ---- main loop: ONE barrier per kt, COUNTED vmcnt (never 0) ----
#pragma unroll 2
  for (int kt = 0; kt < KTILES; ++kt) {
    const int cur = kt & 1;
    const int curb = kt % 3;
    int kt2 = kt + 2; if (kt2 >= KTILES) kt2 = KTILES - 1;  // clamp: lands in
    int ktb = kt + 1; if (ktb >= KTILES) ktb = KTILES - 1;  // unread buffers
    // issue-early: A(kt+2) into the free buffer (read iter kt+2: ~2 iters of
    // cover), B(kt+1) into the spare reg set (consumed after compiler's
    // vmcnt(14) at iter kt+1's MFMAs: body+barrier cover).
    STAGE_A(kt2, ((kt + 2) % 3));
    LOAD_B(ktb, cur ^ 1);
    short8 af[4];
#pragma unroll
    for (int mi = 0; mi < 4; ++mi)  // A-frag: A[m=l16][k=quad*8+j], de-swizzled
      af[mi] = *(const short8*)(
          &As[curb][0] + (wm * 64 + mi * 16 + l16) * 32 + ((quad ^ sw) * 8));
    __builtin_amdgcn_s_setprio(1);
#pragma unroll
    for (int mi = 0; mi < 4; ++mi)
#pragma unroll
      for (int f = 0; f < 6; ++f)
        acc[mi][f] =
            __builtin_amdgcn_mfma_f32_16x16x32_bf16(af[mi], bf[cur][f], acc[mi][f], 0, 0, 0);
    __builtin_amdgcn_s_setprio(0);
    // counted: A(kt+1)'s last load has exactly 26 newer loads
    // (B(kt):12 + A(kt+2):2 + B(kt+1):12) -> vmcnt(26) guarantees As[(kt+1)%3]
    // landed (per-wave); barrier publishes all waves' slices. No drain.
    asm volatile("s_waitcnt vmcnt(26)" ::: "memory");
    __builtin_amdgcn_s_barrier();
    __builtin_amdgcn_sched_barrier(0);
  }
#undef STAGE_A
#undef LOAD_B
  lstm_epilogue(acc, m0, j0, wm, wn, quad, l16, bias, c0, out);
}

// ---------------- Path B GEMM: fp32 staging fallback (no workspace) --------
__global__ __launch_bounds__(256) void gemm_f32_kernel(
    const float* __restrict__ x, const float* __restrict__ h,
    const float* __restrict__ W, const float* __restrict__ Wh,
    const float* __restrict__ bias, const float* __restrict__ c0,
    float* __restrict__ out) {
  __shared__ __align__(16) unsigned short As[128 * 36];  // 72B rows (pad)
  __shared__ __align__(16) unsigned short Bs[192 * 36];
  const int tid = threadIdx.x;
  const int lane = tid & 63, w = tid >> 6;
  const int wm = w >> 1, wn = w & 1;
  const int quad = lane >> 4, l16 = lane & 15;
  const int bx = blockIdx.x;
  const int jt = bx & 31, mt = bx >> 5;
  const int m0 = mt * 128, j0 = jt * 64;

  f32x4 acc[4][6];
#pragma unroll
  for (int a = 0; a < 4; ++a)
#pragma unroll
    for (int b = 0; b < 6; ++b) acc[a][b] = (f32x4){0.f, 0.f, 0.f, 0.f};

  for (int kt = 0; kt < KTILES; ++kt) {
    int k0 = kt * 32;
#pragma unroll
    for (int i = 0; i < 4; ++i) {
      int q = i * 256 + tid;
      int m = q >> 3, kk = (q & 7) * 4;
      int k = k0 + kk;
      const float* src = (k < INSZ) ? (x + (size_t)(m0 + m) * INSZ + k)
                                    : (h + (size_t)(m0 + m) * HID + (k - INSZ));
      float4 v = *(const float4*)src;
      u16x4 o;
      o.x = f32_to_bf16(v.x); o.y = f32_to_bf16(v.y);
      o.z = f32_to_bf16(v.z); o.w = f32_to_bf16(v.w);
      *(u16x4*)(As + m * 36 + kk) = o;
    }
#pragma unroll
    for (int i = 0; i < 6; ++i) {
      int q = i * 256 + tid;
      int n = q % 192, kq = (q / 192) * 4;
      int col = (n >> 6) * HID + j0 + (n & 63);
      float vv[4];
#pragma unroll
      for (int t = 0; t < 4; ++t) {
        int k = k0 + kq + t;
        vv[t] = (k < INSZ) ? W[(size_t)k * NG + col]
                           : Wh[(size_t)(k - INSZ) * NG + col];
      }
      u16x4 o;
      o.x = f32_to_bf16(vv[0]); o.y = f32_to_bf16(vv[1]);
      o.z = f32_to_bf16(vv[2]); o.w = f32_to_bf16(vv[3]);
      *(u16x4*)(Bs + n * 36 + kq) = o;
    }
    __syncthreads();
    short8 af[4], bf[6];
#pragma unroll
    for (int mi = 0; mi < 4; ++mi) {
      int base = (wm * 64 + mi * 16 + l16) * 36 + quad * 8;
      short4v lo = *(const short4v*)(As + base);
      short4v hi = *(const short4v*)(As + base + 4);
      af[mi] = __builtin_shufflevector(lo, hi, 0, 1, 2, 3, 4, 5, 6, 7);
    }
#pragma unroll
    for (int g = 0; g < 3; ++g)
#pragma unroll
      for (int p = 0; p < 2; ++p) {
        int base = (g * 64 + (2 * wn + p) * 16 + l16) * 36 + quad * 8;
        short4v lo = *(const short4v*)(Bs + base);
        short4v hi = *(const short4v*)(Bs + base + 4);
        bf[g * 2 + p] = __builtin_shufflevector(lo, hi, 0, 1, 2, 3, 4, 5, 6, 7);
      }
#pragma unroll
    for (int mi = 0; mi < 4; ++mi)
#pragma unroll
      for (int f = 0; f < 6; ++f)
        acc[mi][f] =
            __builtin_amdgcn_mfma_f32_16x16x32_bf16(af[mi], bf[f], acc[mi][f], 0, 0, 0);
    __syncthreads();
  }
  lstm_epilogue(acc, m0, j0, wm, wn, quad, l16, bias, c0, out);
}

extern "C" void kernel_launch(void* const* d_in, const int* in_sizes, int n_in,
                              void* d_out, int out_size, void* d_ws, size_t ws_size,
                              hipStream_t stream) {
  const float* x    = (const float*)d_in[0];
  const float* h0   = (const float*)d_in[1];
  const float* c0   = (const float*)d_in[2];
  const float* W    = (const float*)d_in[3];
  const float* Wh   = (const float*)d_in[4];
  const float* bias = (const float*)d_in[5];
  float* out = (float*)d_out;

  const size_t needA = (size_t)KTOT * BATCH * 2;  // 48 MB
  const size_t needB = (size_t)KTOT * NG * 2;     // 36 MB
  if (ws_size >= needA + needB) {
    unsigned short* Ap = (unsigned short*)d_ws;
    unsigned short* Bp = Ap + (size_t)KTOT * BATCH;
    pack_ab_kernel<<<PACKA_BLOCKS + PACKB_BLOCKS, 256, 0, stream>>>(x, h0, W, Wh, Ap, Bp);
    gemm_packed_kernel<<<2048, 256, 0, stream>>>(Ap, Bp, bias, c0, out);
  } else {
    gemm_f32_kernel<<<2048, 256, 0, stream>>>(x, h0, W, Wh, bias, c0, out);
  }
}

// Round 5
// 569.371 us; speedup vs baseline: 1.7514x; 1.4483x over previous
//
#include <hip/hip_runtime.h>
#include <stdint.h>

// WordLSTMCell: c1 = sigmoid(f)*c0 + sigmoid(i)*tanh(c),
//   [f|i|c] = x@W + h@Wh + b ;  x:[8192,1024] h,c0:[8192,2048]
//   W:[1024,6144] Wh:[2048,6144] b:[6144]  (all fp32; out fp32 [8192,2048])
//
// Round 7: rounds 5/6 raced on a counted vmcnt(12) that mixed global_load_lds
// with regular global loads under one counter (cross-type FIFO decrement is
// NOT a safe assumption; two hardware failures). Retreat to correct-by-
// construction while keeping the latency-cover win:
//  - dbuf A LDS + ISSUE-EARLY: stage A(kt+1) and load B(kt+1) at the TOP of
//    iter kt, compute on buffer cur, ONE __syncthreads() at the bottom
//    (full vmcnt drain -- but now the drained loads had a whole body of
//    cover, vs round-0's zero cover).
//  - __launch_bounds__(256, 2): dbuf reg state tipped rounds 1/2 to
//    1 block/CU (occ 11.9%); pin 2 blocks/CU.
//  - mt=bx&63 mapping (co-resident blocks share the L2-resident B slice),
//    A-row LDS swizzle, s_setprio around MFMAs, fused pack dispatch: kept.

#define BATCH 8192
#define INSZ  1024
#define HID   2048
#define NG    6144
#define KTOT  3072
#define KTILES 96

typedef __attribute__((ext_vector_type(8))) short short8;
typedef __attribute__((ext_vector_type(4))) short short4v;
typedef __attribute__((ext_vector_type(4))) float f32x4;
typedef __attribute__((ext_vector_type(4))) unsigned short u16x4;

__device__ __forceinline__ unsigned short f32_to_bf16(float f) {
  uint32_t u = __builtin_bit_cast(uint32_t, f);
  u += 0x7fffu + ((u >> 16) & 1u);   // round-to-nearest-even
  return (unsigned short)(u >> 16);
}

// ---------------- fused pack kernel (Path A) ----------------
// Part A (blocks [0,24576)):
//   Apack[kt][m][chunk-swizzled 32] = concat(x,h)[m][kt*32+..], bf16. 48 MB.
//   Within each 64B row, 16B chunk c stored at c ^ ((m + (m>>2)) & 3).
// Part B (blocks [24576,43008)):
//   Bpack[kt][n][kk] = vstack(W,Wh)[kt*32+kk][n], bf16. 36 MB.
#define PACKA_BLOCKS 24576
#define PACKB_BLOCKS 18432
__global__ __launch_bounds__(256) void pack_ab_kernel(
    const float* __restrict__ x, const float* __restrict__ h,
    const float* __restrict__ W, const float* __restrict__ Wh,
    unsigned short* __restrict__ Ap, unsigned short* __restrict__ Bp) {
  if (blockIdx.x < PACKA_BLOCKS) {
    uint32_t q   = blockIdx.x * 256u + threadIdx.x;  // [0, 96*8192*8)
    uint32_t kk4 = q & 7u;           // half-chunk index (4 floats)
    uint32_t m   = (q >> 3) & 8191u;
    uint32_t kt  = q >> 16;
    uint32_t k   = kt * 32u + kk4 * 4u;
    const float* src = (k < INSZ) ? (x + (size_t)m * INSZ + k)
                                  : (h + (size_t)m * HID + (k - INSZ));
    float4 v = *(const float4*)src;
    u16x4 o;
    o.x = f32_to_bf16(v.x); o.y = f32_to_bf16(v.y);
    o.z = f32_to_bf16(v.z); o.w = f32_to_bf16(v.w);
    uint32_t c  = kk4 >> 1, hh = kk4 & 1;
    uint32_t sm = (m + (m >> 2)) & 3u;
    *(u16x4*)(Ap + ((size_t)kt * BATCH + m) * 32 + ((c ^ sm) * 8 + hh * 4)) = o;
  } else {
    uint32_t q  = (blockIdx.x - PACKA_BLOCKS) * 256u + threadIdx.x;  // [0, 96*6144*8)
    uint32_t hh = q & 7u;                            // u16x4 within row
    uint32_t r  = q >> 3;
    uint32_t n  = r % 6144u;
    uint32_t kt = r / 6144u;
    uint32_t k0 = kt * 32u + hh * 4u;
    float v[4];
#pragma unroll
    for (int t = 0; t < 4; ++t) {
      uint32_t k = k0 + t;
      v[t] = (k < INSZ) ? W[(size_t)k * NG + n]
                        : Wh[(size_t)(k - INSZ) * NG + n];
    }
    u16x4 o;
    o.x = f32_to_bf16(v[0]); o.y = f32_to_bf16(v[1]);
    o.z = f32_to_bf16(v[2]); o.w = f32_to_bf16(v[3]);
    *(u16x4*)(Bp + ((size_t)kt * NG + n) * 32 + hh * 4) = o;
  }
}

// ---------------- shared epilogue ----------------
// C-layout (m89-verified): col = lane&15, row = (lane>>4)*4 + reg.
__device__ __forceinline__ void lstm_epilogue(
    const f32x4 acc[4][6], int m0, int j0, int wm, int wn, int quad, int l16,
    const float* __restrict__ bias, const float* __restrict__ c0,
    float* __restrict__ out) {
#pragma unroll
  for (int mi = 0; mi < 4; ++mi) {
    int rowb = m0 + wm * 64 + mi * 16 + quad * 4;
#pragma unroll
    for (int p = 0; p < 2; ++p) {
      int j = j0 + (2 * wn + p) * 16 + l16;
      float bfv = bias[j], biv = bias[HID + j], bcv = bias[2 * HID + j];
#pragma unroll
      for (int r = 0; r < 4; ++r) {
        size_t idx = (size_t)(rowb + r) * HID + j;
        float fg = acc[mi][0 + p][r] + bfv;
        float ig = acc[mi][2 + p][r] + biv;
        float cg = acc[mi][4 + p][r] + bcv;
        float sf = 1.f / (1.f + __expf(-fg));
        float si = 1.f / (1.f + __expf(-ig));
        float th = 2.f / (1.f + __expf(-2.f * cg)) - 1.f;
        out[idx] = sf * c0[idx] + si * th;
      }
    }
  }
}

// ---------------- Path A GEMM: A dbuf LDS (swizzled), B register-direct ----
__global__ __launch_bounds__(256, 2) void gemm_packed_kernel(
    const unsigned short* __restrict__ Ap, const unsigned short* __restrict__ Bp,
    const float* __restrict__ bias, const float* __restrict__ c0,
    float* __restrict__ out) {
  __shared__ __align__(16) unsigned short As[2][128 * 32];  // 2 x 8 KB, swizzled rows
  const int tid = threadIdx.x;
  const int lane = tid & 63, w = tid >> 6;
  const int wm = w >> 1, wn = w & 1;       // waves 2(M) x 2(N-pairs)
  const int quad = lane >> 4, l16 = lane & 15;
  const int bx = blockIdx.x;
  const int mt = bx & 63, jt = bx >> 6;    // co-resident blocks share jt (B slice)
  const int m0 = mt * 128, j0 = jt * 64;
  const int sw = (l16 + (l16 >> 2)) & 3;   // A-row bank swizzle (uniform in mi)

  f32x4 acc[4][6];
#pragma unroll
  for (int a = 0; a < 4; ++a)
#pragma unroll
    for (int b = 0; b < 6; ++b) acc[a][b] = (f32x4){0.f, 0.f, 0.f, 0.f};

  // B fragment base: frag(g,p) at bb + kt*NG*32 + g*(HID*32) + p*512 (shorts)
  const unsigned short* bb =
      Bp + ((size_t)(j0 + 2 * wn * 16 + l16)) * 32 + quad * 8;

#define STAGE_A(ktile, buf)                                                    \
  {                                                                            \
    const unsigned short* ga = Ap + ((size_t)(ktile) * BATCH + m0) * 32;       \
    _Pragma("unroll")                                                          \
    for (int i = 0; i < 2; ++i) {                                              \
      int t2 = w * 2 + i;                                                      \
      __builtin_amdgcn_global_load_lds(                                        \
          (__attribute__((address_space(1))) void*)(void*)(ga + t2 * 512 +     \
                                                           lane * 8),          \
          (__attribute__((address_space(3))) void*)(&As[(buf)][0] + t2 * 512), \
          16, 0, 0);                                                           \
    }                                                                          \
  }

#define LOAD_B(ktile, idx)                                                     \
  {                                                                            \
    const unsigned short* bn = bb + (size_t)(ktile) * ((size_t)NG * 32);       \
    _Pragma("unroll")                                                          \
    for (int g = 0; g < 3; ++g)                                                \
      _Pragma("unroll")                                                        \
      for (int p = 0; p < 2; ++p)                                              \
        bf[(idx)][g * 2 + p] = *(const short8*)(bn + g * (HID * 32) + p * 512);\
  }

  short8 bf[2][6];
  // ---- prologue: A(0)->As[0], B(0)->bf[0]; full drain (correct, cheap) ----
  STAGE_A(0, 0);
  LOAD_B(0, 0);
  __syncthreads();   // vmcnt(0) lgkmcnt(0) + barrier: A(0)/B(0) landed

  // ---- main loop: issue-early prefetch, compute, ONE full-drain barrier ----
  // Correctness needs NO vmem-ordering assumptions: __syncthreads drains all.
  // The drained loads were issued a full body earlier -> residual wait only.
#pragma unroll 2
  for (int kt = 0; kt < KTILES; ++kt) {
    const int cur = kt & 1;
    int ktn = kt + 1; if (ktn >= KTILES) ktn = KTILES - 1;  // clamp: last-iter
    // prefetch lands in the unread buffer/regs (branch-free tail)
    STAGE_A(ktn, cur ^ 1);
    LOAD_B(ktn, cur ^ 1);
    short8 af[4];
#pragma unroll
    for (int mi = 0; mi < 4; ++mi)  // A-frag: A[m=l16][k=quad*8+j], de-swizzled
      af[mi] = *(const short8*)(
          &As[cur][0] + (wm * 64 + mi * 16 + l16) * 32 + ((quad ^ sw) * 8));
    __builtin_amdgcn_s_setprio(1);
#pragma unroll
    for (int mi = 0; mi < 4; ++mi)
#pragma unroll
      for (int f = 0; f < 6; ++f)
        acc[mi][f] =
            __builtin_amdgcn_mfma_f32_16x16x32_bf16(af[mi], bf[cur][f], acc[mi][f], 0, 0, 0);
    __builtin_amdgcn_s_setprio(0);
    // full drain: publishes A(kt+1) LDS-DMA (all waves) before next iter's
    // ds_reads; B(kt+1) regs also drained (residual only -- body of cover).
    __syncthreads();
  }
#undef STAGE_A
#undef LOAD_B
  lstm_epilogue(acc, m0, j0, wm, wn, quad, l16, bias, c0, out);
}

// ---------------- Path B GEMM: fp32 staging fallback (no workspace) --------
__global__ __launch_bounds__(256) void gemm_f32_kernel(
    const float* __restrict__ x, const float* __restrict__ h,
    const float* __restrict__ W, const float* __restrict__ Wh,
    const float* __restrict__ bias, const float* __restrict__ c0,
    float* __restrict__ out) {
  __shared__ __align__(16) unsigned short As[128 * 36];  // 72B rows (pad)
  __shared__ __align__(16) unsigned short Bs[192 * 36];
  const int tid = threadIdx.x;
  const int lane = tid & 63, w = tid >> 6;
  const int wm = w >> 1, wn = w & 1;
  const int quad = lane >> 4, l16 = lane & 15;
  const int bx = blockIdx.x;
  const int jt = bx & 31, mt = bx >> 5;
  const int m0 = mt * 128, j0 = jt * 64;

  f32x4 acc[4][6];
#pragma unroll
  for (int a = 0; a < 4; ++a)
#pragma unroll
    for (int b = 0; b < 6; ++b) acc[a][b] = (f32x4){0.f, 0.f, 0.f, 0.f};

  for (int kt = 0; kt < KTILES; ++kt) {
    int k0 = kt * 32;
#pragma unroll
    for (int i = 0; i < 4; ++i) {
      int q = i * 256 + tid;
      int m = q >> 3, kk = (q & 7) * 4;
      int k = k0 + kk;
      const float* src = (k < INSZ) ? (x + (size_t)(m0 + m) * INSZ + k)
                                    : (h + (size_t)(m0 + m) * HID + (k - INSZ));
      float4 v = *(const float4*)src;
      u16x4 o;
      o.x = f32_to_bf16(v.x); o.y = f32_to_bf16(v.y);
      o.z = f32_to_bf16(v.z); o.w = f32_to_bf16(v.w);
      *(u16x4*)(As + m * 36 + kk) = o;
    }
#pragma unroll
    for (int i = 0; i < 6; ++i) {
      int q = i * 256 + tid;
      int n = q % 192, kq = (q / 192) * 4;
      int col = (n >> 6) * HID + j0 + (n & 63);
      float vv[4];
#pragma unroll
      for (int t = 0; t < 4; ++t) {
        int k = k0 + kq + t;
        vv[t] = (k < INSZ) ? W[(size_t)k * NG + col]
                           : Wh[(size_t)(k - INSZ) * NG + col];
      }
      u16x4 o;
      o.x = f32_to_bf16(vv[0]); o.y = f32_to_bf16(vv[1]);
      o.z = f32_to_bf16(vv[2]); o.w = f32_to_bf16(vv[3]);
      *(u16x4*)(Bs + n * 36 + kq) = o;
    }
    __syncthreads();
    short8 af[4], bf[6];
#pragma unroll
    for (int mi = 0; mi < 4; ++mi) {
      int base = (wm * 64 + mi * 16 + l16) * 36 + quad * 8;
      short4v lo = *(const short4v*)(As + base);
      short4v hi = *(const short4v*)(As + base + 4);
      af[mi] = __builtin_shufflevector(lo, hi, 0, 1, 2, 3, 4, 5, 6, 7);
    }
#pragma unroll
    for (int g = 0; g < 3; ++g)
#pragma unroll
      for (int p = 0; p < 2; ++p) {
        int base = (g * 64 + (2 * wn + p) * 16 + l16) * 36 + quad * 8;
        short4v lo = *(const short4v*)(Bs + base);
        short4v hi = *(const short4v*)(Bs + base + 4);
        bf[g * 2 + p] = __builtin_shufflevector(lo, hi, 0, 1, 2, 3, 4, 5, 6, 7);
      }
#pragma unroll
    for (int mi = 0; mi < 4; ++mi)
#pragma unroll
      for (int f = 0; f < 6; ++f)
        acc[mi][f] =
            __builtin_amdgcn_mfma_f32_16x16x32_bf16(af[mi], bf[f], acc[mi][f], 0, 0, 0);
    __syncthreads();
  }
  lstm_epilogue(acc, m0, j0, wm, wn, quad, l16, bias, c0, out);
}

extern "C" void kernel_launch(void* const* d_in, const int* in_sizes, int n_in,
                              void* d_out, int out_size, void* d_ws, size_t ws_size,
                              hipStream_t stream) {
  const float* x    = (const float*)d_in[0];
  const float* h0   = (const float*)d_in[1];
  const float* c0   = (const float*)d_in[2];
  const float* W    = (const float*)d_in[3];
  const float* Wh   = (const float*)d_in[4];
  const float* bias = (const float*)d_in[5];
  float* out = (float*)d_out;

  const size_t needA = (size_t)KTOT * BATCH * 2;  // 48 MB
  const size_t needB = (size_t)KTOT * NG * 2;     // 36 MB
  if (ws_size >= needA + needB) {
    unsigned short* Ap = (unsigned short*)d_ws;
    unsigned short* Bp = Ap + (size_t)KTOT * BATCH;
    pack_ab_kernel<<<PACKA_BLOCKS + PACKB_BLOCKS, 256, 0, stream>>>(x, h0, W, Wh, Ap, Bp);
    gemm_packed_kernel<<<2048, 256, 0, stream>>>(Ap, Bp, bias, c0, out);
  } else {
    gemm_f32_kernel<<<2048, 256, 0, stream>>>(x, h0, W, Wh, bias, c0, out);
  }
}